// Round 10
// baseline (2425.093 us; speedup 1.0000x reference)
//
#include <hip/hip_runtime.h>
#include <hip/hip_bf16.h>
#include <hip/hip_cooperative_groups.h>

namespace cg = cooperative_groups;

#define TXN 256   // Tx
#define NA 256    // n_a
#define NF 128    // features
#define NS 512    // n_s
#define TYN 10
#define VOCAB 1024

// ---- encoder LDS layout (split-bf16 planes) ----
#define A_STR 392
#define W_STR 392
#define WL_OFF (64 * W_STR)
#define AH_OFF (2 * 64 * W_STR)
#define AL_OFF (AH_OFF + 32 * A_STR)
#define PRE_OFF_US (AL_OFF + 32 * A_STR)
#define ENC_LDS_BYTES (150528 + 32 * 68 * 4 + 64 * 4)   // 159,488 B

// ---- decoder MFMA-GEMM LDS layout (ushort indices), K-chunk = 256 ----
#define D_STR 264                        // 256 + 8 pad
#define D_WH 0
#define D_WL (64 * D_STR)                // 16896
#define D_AH (2 * 64 * D_STR)            // 33792
#define D_AL (D_AH + 32 * D_STR)         // 42240
#define D_PRE_US (D_AL + 32 * D_STR)     // 50688 -> byte 101376
#define DEC_LDS_BYTES (101376 + 32 * 68 * 4 + 64 * 4)   // 110,336 B

typedef __attribute__((ext_vector_type(8))) short bf16x8;
typedef __attribute__((ext_vector_type(4))) float f32x4;

__device__ __forceinline__ float fsigmoid(float x) { return 1.f / (1.f + __expf(-x)); }
__device__ __forceinline__ float ftanh(float x)    { return 1.f - 2.f / (1.f + __expf(2.f * x)); }

__device__ __forceinline__ void split_bf16(float v, unsigned short& hi, unsigned short& lo) {
    __hip_bfloat16 h = __float2bfloat16(v);
    float rem = v - __bfloat162float(h);
    __hip_bfloat16 l = __float2bfloat16(rem);
    hi = *reinterpret_cast<unsigned short*>(&h);
    lo = *reinterpret_cast<unsigned short*>(&l);
}

__device__ __forceinline__ float agent_ld(const float* p) {
    return __hip_atomic_load(p, __ATOMIC_RELAXED, __HIP_MEMORY_SCOPE_AGENT);
}
__device__ __forceinline__ void agent_st(float* p, float v) {
    __hip_atomic_store(p, v, __ATOMIC_RELAXED, __HIP_MEMORY_SCOPE_AGENT);
}
__device__ __forceinline__ unsigned flag_ld(const unsigned* p) {
    return __hip_atomic_load(p, __ATOMIC_RELAXED, __HIP_MEMORY_SCOPE_AGENT);
}
__device__ __forceinline__ void flag_st(unsigned* p, unsigned v) {
    __hip_atomic_store(p, v, __ATOMIC_RELAXED, __HIP_MEMORY_SCOPE_AGENT);
}

// ---------------------------------------------------------------------------
// Persistent bidirectional LSTM encoder — MFMA split-bf16, per-producer flags.
// (unchanged from R7, verified passing)
// ---------------------------------------------------------------------------
__global__ __launch_bounds__(256, 1) void encoder_kernel(
    const float* __restrict__ X,
    const float* __restrict__ Wih_f, const float* __restrict__ Whh_f, const float* __restrict__ b_f,
    const float* __restrict__ Wih_b, const float* __restrict__ Whh_b, const float* __restrict__ b_b,
    float* __restrict__ a, unsigned int* __restrict__ bar)
{
    extern __shared__ unsigned char smem_raw[];
    unsigned short* Wh  = (unsigned short*)smem_raw;
    unsigned short* Wl  = (unsigned short*)smem_raw + WL_OFF;
    unsigned short* Ahh = (unsigned short*)smem_raw + AH_OFF;
    unsigned short* All = (unsigned short*)smem_raw + AL_OFF;
    float* Pre = (float*)(smem_raw + (size_t)PRE_OFF_US * 2);   // [32][68]
    float* bsh = Pre + 32 * 68;                                  // [64]

    const int tid = threadIdx.x;
    const int dir = blockIdx.x & 1;
    const int bid = blockIdx.x >> 1;
    const int i0 = (bid >> 4) * 32;
    const int j0 = (bid & 15) * 16;
    const int grp = dir * 8 + (bid >> 4);
    const int myjb = bid & 15;
    unsigned int* slots = bar + grp * 16;

    const float* __restrict__ Wih = dir ? Wih_b : Wih_f;
    const float* __restrict__ Whh = dir ? Whh_b : Whh_f;
    const float* __restrict__ bv  = dir ? b_b  : b_f;

    const int jl = tid & 15;
    const int ip = tid >> 4;
    const int iA = ip * 2;

    if (tid < 64) bsh[tid] = bv[(tid >> 4) * NA + j0 + (tid & 15)];
    for (int r = 0; r < 64; ++r) {
        int row = (r >> 4) * NA + j0 + (r & 15);
        unsigned short hi, lo;
        split_bf16(Whh[(size_t)row * NA + tid], hi, lo);
        Wh[r * W_STR + tid] = hi;
        Wl[r * W_STR + tid] = lo;
        if (tid < NF) {
            split_bf16(Wih[(size_t)row * NF + tid], hi, lo);
            Wh[r * W_STR + 256 + tid] = hi;
            Wl[r * W_STR + 256 + tid] = lo;
        }
    }

    #pragma unroll 4
    for (int r = 0; r < 32; ++r) {
        Ahh[r * A_STR + tid] = 0;
        All[r * A_STR + tid] = 0;
    }
    {
        const int t0 = dir ? (TXN - 1) : 0;
        const int kx = tid & 127;
        const int rbase = tid >> 7;
        #pragma unroll 4
        for (int rr = 0; rr < 16; ++rr) {
            int r = rr * 2 + rbase;
            float v = X[((size_t)(i0 + r) * TXN + t0) * NF + kx];
            unsigned short hi, lo;
            split_bf16(v, hi, lo);
            Ahh[r * A_STR + 256 + kx] = hi;
            All[r * A_STR + 256 + kx] = lo;
        }
    }

    float c0 = 0.f, c1 = 0.f;

    const int lane = tid & 63;
    const int wv   = tid >> 6;
    const int rt   = wv >> 1;
    const int g0   = (wv & 1) * 2;
    const int ln   = lane & 15;
    const int quad = lane >> 4;
    const unsigned short* pAh = Ahh + (rt * 16 + ln) * A_STR + quad * 8;
    const unsigned short* pAl = All + (rt * 16 + ln) * A_STR + quad * 8;
    const unsigned short* pW0h = Wh + (g0 * 16 + ln) * W_STR + quad * 8;
    const unsigned short* pW0l = Wl + (g0 * 16 + ln) * W_STR + quad * 8;
    const unsigned short* pW1h = pW0h + 16 * W_STR;
    const unsigned short* pW1l = pW0l + 16 * W_STR;

    for (int step = 0; step < TXN; ++step) {
        const int t = dir ? (TXN - 1 - step) : step;

        if (step != 0) {
            const int tprev = dir ? (t + 1) : (t - 1);
            const int jb = tid >> 4;
            while (flag_ld(&slots[jb]) < (unsigned)step) {}
            float hv[32];
            #pragma unroll
            for (int r = 0; r < 32; ++r) {
                hv[r] = agent_ld(&a[(((size_t)(i0 + r) * TXN + tprev) << 9) + dir * NA + tid]);
            }
            #pragma unroll
            for (int r = 0; r < 32; ++r) {
                unsigned short hi, lo;
                split_bf16(hv[r], hi, lo);
                Ahh[r * A_STR + tid] = hi;
                All[r * A_STR + tid] = lo;
            }
        }
        __syncthreads();

        f32x4 a0e = {0.f,0.f,0.f,0.f}, a0o = {0.f,0.f,0.f,0.f};
        f32x4 a1e = {0.f,0.f,0.f,0.f}, a1o = {0.f,0.f,0.f,0.f};
        #pragma unroll
        for (int kp = 0; kp < 6; ++kp) {
            {
                const int kc = kp * 2;
                bf16x8 fah = *(const bf16x8*)(pAh + kc * 32);
                bf16x8 fal = *(const bf16x8*)(pAl + kc * 32);
                bf16x8 w0h = *(const bf16x8*)(pW0h + kc * 32);
                bf16x8 w0l = *(const bf16x8*)(pW0l + kc * 32);
                bf16x8 w1h = *(const bf16x8*)(pW1h + kc * 32);
                bf16x8 w1l = *(const bf16x8*)(pW1l + kc * 32);
                a0e = __builtin_amdgcn_mfma_f32_16x16x32_bf16(fal, w0h, a0e, 0, 0, 0);
                a0e = __builtin_amdgcn_mfma_f32_16x16x32_bf16(fah, w0l, a0e, 0, 0, 0);
                a0e = __builtin_amdgcn_mfma_f32_16x16x32_bf16(fah, w0h, a0e, 0, 0, 0);
                a1e = __builtin_amdgcn_mfma_f32_16x16x32_bf16(fal, w1h, a1e, 0, 0, 0);
                a1e = __builtin_amdgcn_mfma_f32_16x16x32_bf16(fah, w1l, a1e, 0, 0, 0);
                a1e = __builtin_amdgcn_mfma_f32_16x16x32_bf16(fah, w1h, a1e, 0, 0, 0);
            }
            {
                const int kc = kp * 2 + 1;
                bf16x8 fah = *(const bf16x8*)(pAh + kc * 32);
                bf16x8 fal = *(const bf16x8*)(pAl + kc * 32);
                bf16x8 w0h = *(const bf16x8*)(pW0h + kc * 32);
                bf16x8 w0l = *(const bf16x8*)(pW0l + kc * 32);
                bf16x8 w1h = *(const bf16x8*)(pW1h + kc * 32);
                bf16x8 w1l = *(const bf16x8*)(pW1l + kc * 32);
                a0o = __builtin_amdgcn_mfma_f32_16x16x32_bf16(fal, w0h, a0o, 0, 0, 0);
                a0o = __builtin_amdgcn_mfma_f32_16x16x32_bf16(fah, w0l, a0o, 0, 0, 0);
                a0o = __builtin_amdgcn_mfma_f32_16x16x32_bf16(fah, w0h, a0o, 0, 0, 0);
                a1o = __builtin_amdgcn_mfma_f32_16x16x32_bf16(fal, w1h, a1o, 0, 0, 0);
                a1o = __builtin_amdgcn_mfma_f32_16x16x32_bf16(fah, w1l, a1o, 0, 0, 0);
                a1o = __builtin_amdgcn_mfma_f32_16x16x32_bf16(fah, w1h, a1o, 0, 0, 0);
            }
        }
        #pragma unroll
        for (int reg = 0; reg < 4; ++reg) {
            int prow = rt * 16 + quad * 4 + reg;
            Pre[prow * 68 + g0 * 16 + ln]       = a0e[reg] + a0o[reg];
            Pre[prow * 68 + (g0 + 1) * 16 + ln] = a1e[reg] + a1o[reg];
        }
        __syncthreads();

        float h0, h1;
        {
            float gi = fsigmoid(Pre[iA * 68 +      jl] + bsh[jl]);
            float gf = fsigmoid(Pre[iA * 68 + 16 + jl] + bsh[16 + jl]);
            float gg = ftanh  (Pre[iA * 68 + 32 + jl] + bsh[32 + jl]);
            float go = fsigmoid(Pre[iA * 68 + 48 + jl] + bsh[48 + jl]);
            c0 = gf * c0 + gi * gg;
            h0 = go * ftanh(c0);
        }
        {
            float gi = fsigmoid(Pre[(iA + 1) * 68 +      jl] + bsh[jl]);
            float gf = fsigmoid(Pre[(iA + 1) * 68 + 16 + jl] + bsh[16 + jl]);
            float gg = ftanh  (Pre[(iA + 1) * 68 + 32 + jl] + bsh[32 + jl]);
            float go = fsigmoid(Pre[(iA + 1) * 68 + 48 + jl] + bsh[48 + jl]);
            c1 = gf * c1 + gi * gg;
            h1 = go * ftanh(c1);
        }
        agent_st(&a[(((size_t)(i0 + iA)     * TXN + t) << 9) + dir * NA + j0 + jl], h0);
        agent_st(&a[(((size_t)(i0 + iA + 1) * TXN + t) << 9) + dir * NA + j0 + jl], h1);

        if (step != TXN - 1) {
            __syncthreads();
            if (tid == 0) flag_st(&slots[myjb], (unsigned)(step + 1));
            {
                const int tn = dir ? (t - 1) : (t + 1);
                const int kx = tid & 127;
                const int rbase = tid >> 7;
                #pragma unroll 4
                for (int rr = 0; rr < 16; ++rr) {
                    int r = rr * 2 + rbase;
                    float v = X[((size_t)(i0 + r) * TXN + tn) * NF + kx];
                    unsigned short hi, lo;
                    split_bf16(v, hi, lo);
                    Ahh[r * A_STR + 256 + kx] = hi;
                    All[r * A_STR + 256 + kx] = lo;
                }
            }
        }
    }
}

// ---------------------------------------------------------------------------
// Weight split kernels: fp32 -> bf16 hi/lo planes.
// ---------------------------------------------------------------------------
__global__ __launch_bounds__(256) void wsplit_cat(
    const float* __restrict__ Wc_ih, const float* __restrict__ Wc_hh,
    unsigned short* __restrict__ Wh, unsigned short* __restrict__ Wl)
{
    int idx = blockIdx.x * 256 + threadIdx.x;   // 2048*1024
    int r = idx >> 10, k = idx & 1023;
    float v = (k < 512) ? Wc_ih[(size_t)r * 512 + k] : Wc_hh[(size_t)r * 512 + (k - 512)];
    unsigned short hi, lo;
    split_bf16(v, hi, lo);
    Wh[idx] = hi; Wl[idx] = lo;
}

__global__ __launch_bounds__(256) void wsplit_fc(
    const float* __restrict__ Wfc,
    unsigned short* __restrict__ Wh, unsigned short* __restrict__ Wl)
{
    int idx = blockIdx.x * 256 + threadIdx.x;   // 1024*512
    unsigned short hi, lo;
    split_bf16(Wfc[idx], hi, lo);
    Wh[idx] = hi; Wl[idx] = lo;
}

// ---------------------------------------------------------------------------
// Tall-skinny: aW1[m*Tx][10] = a[m*Tx][512] @ W1[:, :512]^T + b1
// ---------------------------------------------------------------------------
__global__ __launch_bounds__(256) void attn_prep(
    const float* __restrict__ a, const float* __restrict__ W1,
    const float* __restrict__ b1, float* __restrict__ aW1)
{
    __shared__ float Wsh[10][516];
    __shared__ float red[64][10][4];
    const int tid = threadIdx.x;
    for (int idx = tid; idx < 10 * 512; idx += 256) {
        int o = idx >> 9, k = idx & 511;
        Wsh[o][k] = W1[o * 1024 + k];
    }
    __syncthreads();
    const int r = tid >> 2, kq = tid & 3;
    const float* ar = a + ((size_t)blockIdx.x * 64 + r) * 512 + kq * 128;
    float acc[10] = {};
    for (int k = 0; k < 128; k += 4) {
        float4 v = *(const float4*)&ar[k];
        #pragma unroll
        for (int o = 0; o < 10; ++o) {
            float4 w = *(const float4*)&Wsh[o][kq * 128 + k];
            acc[o] += v.x * w.x + v.y * w.y + v.z * w.z + v.w * w.w;
        }
    }
    #pragma unroll
    for (int o = 0; o < 10; ++o) red[r][o][kq] = acc[o];
    __syncthreads();
    for (int idx = tid; idx < 640; idx += 256) {
        int rr = idx / 10, o = idx % 10;
        float s = red[rr][o][0] + red[rr][o][1] + red[rr][o][2] + red[rr][o][3] + b1[o];
        aW1[((size_t)blockIdx.x * 64 + rr) * 10 + o] = s;
    }
}

// ---------------------------------------------------------------------------
// Persistent fused decoder (R10): attention -> gates(+cell) -> logits for all
// TYN iterations, one cooperative kernel, 256 blocks x 256 threads.
// s is PING-PONG buffered: s(ty) = sbuf[ty&1], s(ty+1) = sbuf[(ty+1)&1] —
// removes the R9 WAR race (concurrent read of s(ty) while another block
// writes s(ty+1)). xcat holds ctx only (256 x 512).
// Flags: attn_slot/gates_slot/log_slot (256 each), monotone, write-through
// agent stores after __syncthreads vmcnt-drain; consumers poll then barrier.
// Wait-graph per iteration: A waits gates>=ty; B waits attn>=ty+1, gates>=ty,
// log>=ty; C waits gates>=ty+1 -> acyclic, deadlock-free, WAR-safe.
// ---------------------------------------------------------------------------
__global__ __launch_bounds__(256, 1) void decoder_kernel(
    const float* __restrict__ aW1,   // (m*Tx, 10) b1-added
    const float* __restrict__ a,     // (m, Tx, 512)
    const float* __restrict__ W1,    // (10, 1024)
    const float* __restrict__ W2,    // (10,)
    const float* __restrict__ b2,    // (1,)
    const unsigned short* __restrict__ Wch,  // (2048,1024) hi
    const unsigned short* __restrict__ Wcl,  // lo
    const float* __restrict__ bc,    // (2048,)
    const unsigned short* __restrict__ Wfh,  // (1024,512) hi
    const unsigned short* __restrict__ Wfl,  // lo
    const float* __restrict__ bfc,   // (1024,)
    float* __restrict__ sbufA,       // (256,512)  s parity 0 (zero-init)
    float* __restrict__ sbufB,       // (256,512)  s parity 1
    float* __restrict__ xcat,        // (256,512)  ctx
    float* __restrict__ out,         // (256, TYN, 1024)
    unsigned int* __restrict__ slots)  // attn[256] | gates[256] | log[256]
{
    extern __shared__ unsigned char smem_raw[];
    unsigned short* Wh = (unsigned short*)smem_raw + D_WH;
    unsigned short* Wl = (unsigned short*)smem_raw + D_WL;
    unsigned short* Ah = (unsigned short*)smem_raw + D_AH;
    unsigned short* Al = (unsigned short*)smem_raw + D_AL;
    float* Pre = (float*)(smem_raw + (size_t)D_PRE_US * 2);   // [32][68]
    // phase-A scratch overlays the W region (phases separated by barriers)
    float* F     = (float*)smem_raw;
    float* Aal   = F;            // 256
    float* Ared  = F + 256;      // 256
    float* Asred = F + 512;      // 160
    float* Ash_s = F + 672;      // 10
    float* Ash_w2= F + 682;      // 10
    float4* Actx = (float4*)(F + 704);   // 256 float4

    unsigned int* attn_slot  = slots;
    unsigned int* gates_slot = slots + 256;
    unsigned int* log_slot   = slots + 512;

    const int tid = threadIdx.x;
    const int b   = blockIdx.x;       // attention row
    const int it  = b >> 5;           // i-tile (32 rows)
    const int jt  = b & 31;           // gates j-tile / logits col-tile
    const int i0  = it * 32;
    const int j0  = jt * 16;
    const int v0  = jt * 32;

    const int lane = tid & 63;
    const int wv   = tid >> 6;
    const int rt   = wv >> 1;
    const int g0   = (wv & 1) * 2;
    const int ct   = wv & 1;
    const int ln   = lane & 15;
    const int quad = lane >> 4;
    const int jl   = tid & 15;
    const int iA   = (tid >> 4) * 2;

    const unsigned short* pAh = Ah + (rt * 16 + ln) * D_STR + quad * 8;
    const unsigned short* pAl = Al + (rt * 16 + ln) * D_STR + quad * 8;
    const unsigned short* pGW0h = Wh + (g0 * 16 + ln) * D_STR + quad * 8;
    const unsigned short* pGW0l = Wl + (g0 * 16 + ln) * D_STR + quad * 8;
    const unsigned short* pGW1h = pGW0h + 16 * D_STR;
    const unsigned short* pGW1l = pGW0l + 16 * D_STR;
    const unsigned short* pLWh = Wh + (ct * 16 + ln) * D_STR + quad * 8;
    const unsigned short* pLWl = Wl + (ct * 16 + ln) * D_STR + quad * 8;

    const float bgi = bc[0 * 512 + j0 + jl];
    const float bgf = bc[1 * 512 + j0 + jl];
    const float bgg = bc[2 * 512 + j0 + jl];
    const float bgo = bc[3 * 512 + j0 + jl];

    float c0 = 0.f, c1 = 0.f;   // persistent cell state across iterations

    for (int ty = 0; ty < TYN; ++ty) {
        float* sp = (ty & 1) ? sbufB : sbufA;        // s(ty)
        float* sn = (ty & 1) ? sbufA : sbufB;        // s(ty+1)

        // ================= Phase A: attention for row b =================
        if (tid < 32) {
            while (flag_ld(&gates_slot[it * 32 + tid]) < (unsigned)ty) {}
        }
        __syncthreads();

        if (tid < 160) {
            int o = tid >> 4, part = tid & 15;
            const float* srow = sp + (size_t)b * 512;
            const float* wrow = W1 + o * 1024 + 512;
            float p = 0.f;
            for (int k = part; k < 512; k += 16) p += agent_ld(&srow[k]) * wrow[k];
            Asred[tid] = p;
        }
        __syncthreads();
        if (tid < 10) {
            float v = 0.f;
            #pragma unroll
            for (int p = 0; p < 16; ++p) v += Asred[tid * 16 + p];
            Ash_s[tid] = v;
            Ash_w2[tid] = W2[tid];
        }
        __syncthreads();

        float sum = b2[0];
        {
            const float* ar = aW1 + ((size_t)b * TXN + tid) * 10;
            #pragma unroll
            for (int h = 0; h < 10; ++h) sum += ftanh(ar[h] + Ash_s[h]) * Ash_w2[h];
        }
        float sc = fmaxf(sum, 0.f);

        Ared[tid] = sc;
        __syncthreads();
        for (int s = 128; s > 0; s >>= 1) {
            if (tid < s) Ared[tid] = fmaxf(Ared[tid], Ared[tid + s]);
            __syncthreads();
        }
        float mx = Ared[0];
        __syncthreads();
        float p = __expf(sc - mx);
        Ared[tid] = p;
        __syncthreads();
        for (int s = 128; s > 0; s >>= 1) {
            if (tid < s) Ared[tid] += Ared[tid + s];
            __syncthreads();
        }
        float inv = 1.f / Ared[0];
        Aal[tid] = p * inv;
        __syncthreads();

        {
            const int half = tid >> 7;
            const int q    = tid & 127;
            const float* abase = a + (size_t)b * TXN * NS + q * 4;
            float4 acc = make_float4(0.f, 0.f, 0.f, 0.f);
            #pragma unroll 8
            for (int t = half; t < TXN; t += 2) {
                float w = Aal[t];
                float4 v = *(const float4*)&abase[(size_t)t * NS];
                acc.x += w * v.x; acc.y += w * v.y; acc.z += w * v.z; acc.w += w * v.w;
            }
            Actx[tid] = acc;
        }
        __syncthreads();
        if (tid < 128) {
            float4 e = Actx[tid];
            float4 o = Actx[tid + 128];
            float* dst = &xcat[(size_t)b * 512 + tid * 4];
            agent_st(dst + 0, e.x + o.x);
            agent_st(dst + 1, e.y + o.y);
            agent_st(dst + 2, e.z + o.z);
            agent_st(dst + 3, e.w + o.w);
        }
        __syncthreads();   // drain ctx stores (vmcnt0) before flag
        if (tid == 0) flag_st(&attn_slot[b], (unsigned)(ty + 1));

        // ============ Phase B: gates tile (it, jt) + fused cell ============
        if (tid < 32) {
            while (flag_ld(&attn_slot[i0 + tid]) < (unsigned)(ty + 1)) {}
        } else if (tid < 64) {
            while (flag_ld(&gates_slot[it * 32 + (tid - 32)]) < (unsigned)ty) {}
        } else if (tid < 96) {
            while (flag_ld(&log_slot[it * 32 + (tid - 64)]) < (unsigned)ty) {}
        }

        f32x4 ga0 = {0.f,0.f,0.f,0.f}, ga1 = {0.f,0.f,0.f,0.f};
        {
            const int rW = tid >> 2;
            const int qW = (tid & 3) * 64;
            const int rowg = (rW >> 4) * 512 + j0 + (rW & 15);
            for (int ch = 0; ch < 4; ++ch) {
                const int kc0 = ch * 256;
                __syncthreads();
                // stage A chunk: cols 0..511 = ctx (xcat), 512..1023 = s(ty) (sp)
                #pragma unroll 8
                for (int r = 0; r < 32; ++r) {
                    float v;
                    if (ch < 2) v = agent_ld(&xcat[(size_t)(i0 + r) * 512 + kc0 + tid]);
                    else        v = agent_ld(&sp[(size_t)(i0 + r) * 512 + (kc0 - 512) + tid]);
                    unsigned short hi, lo;
                    split_bf16(v, hi, lo);
                    Ah[r * D_STR + tid] = hi;
                    Al[r * D_STR + tid] = lo;
                }
                {
                    const size_t base = (size_t)rowg * 1024 + kc0 + qW;
                    #pragma unroll
                    for (int i = 0; i < 8; ++i) {
                        *(bf16x8*)&Wh[rW * D_STR + qW + i * 8] = *(const bf16x8*)&Wch[base + i * 8];
                        *(bf16x8*)&Wl[rW * D_STR + qW + i * 8] = *(const bf16x8*)&Wcl[base + i * 8];
                    }
                }
                __syncthreads();
                #pragma unroll
                for (int kc = 0; kc < 8; ++kc) {
                    bf16x8 fah = *(const bf16x8*)(pAh + kc * 32);
                    bf16x8 fal = *(const bf16x8*)(pAl + kc * 32);
                    bf16x8 w0h = *(const bf16x8*)(pGW0h + kc * 32);
                    bf16x8 w0l = *(const bf16x8*)(pGW0l + kc * 32);
                    bf16x8 w1h = *(const bf16x8*)(pGW1h + kc * 32);
                    bf16x8 w1l = *(const bf16x8*)(pGW1l + kc * 32);
                    ga0 = __builtin_amdgcn_mfma_f32_16x16x32_bf16(fal, w0h, ga0, 0, 0, 0);
                    ga0 = __builtin_amdgcn_mfma_f32_16x16x32_bf16(fah, w0l, ga0, 0, 0, 0);
                    ga0 = __builtin_amdgcn_mfma_f32_16x16x32_bf16(fah, w0h, ga0, 0, 0, 0);
                    ga1 = __builtin_amdgcn_mfma_f32_16x16x32_bf16(fal, w1h, ga1, 0, 0, 0);
                    ga1 = __builtin_amdgcn_mfma_f32_16x16x32_bf16(fah, w1l, ga1, 0, 0, 0);
                    ga1 = __builtin_amdgcn_mfma_f32_16x16x32_bf16(fah, w1h, ga1, 0, 0, 0);
                }
            }
        }
        __syncthreads();
        #pragma unroll
        for (int reg = 0; reg < 4; ++reg) {
            int prow = rt * 16 + quad * 4 + reg;
            Pre[prow * 68 + g0 * 16 + ln]       = ga0[reg];
            Pre[prow * 68 + (g0 + 1) * 16 + ln] = ga1[reg];
        }
        __syncthreads();

        // fused cell: thread -> rows (iA, iA+1) x unit jl; write s(ty+1) -> sn
        {
            float gi = fsigmoid(Pre[iA * 68 +      jl] + bgi);
            float gf = fsigmoid(Pre[iA * 68 + 16 + jl] + bgf);
            float gg = ftanh  (Pre[iA * 68 + 32 + jl] + bgg);
            float go = fsigmoid(Pre[iA * 68 + 48 + jl] + bgo);
            c0 = gf * c0 + gi * gg;
            agent_st(&sn[(size_t)(i0 + iA) * 512 + j0 + jl], go * ftanh(c0));
        }
        {
            float gi = fsigmoid(Pre[(iA + 1) * 68 +      jl] + bgi);
            float gf = fsigmoid(Pre[(iA + 1) * 68 + 16 + jl] + bgf);
            float gg = ftanh  (Pre[(iA + 1) * 68 + 32 + jl] + bgg);
            float go = fsigmoid(Pre[(iA + 1) * 68 + 48 + jl] + bgo);
            c1 = gf * c1 + gi * gg;
            agent_st(&sn[(size_t)(i0 + iA + 1) * 512 + j0 + jl], go * ftanh(c1));
        }
        __syncthreads();   // drain s stores before flag
        if (tid == 0) flag_st(&gates_slot[it * 32 + jt], (unsigned)(ty + 1));

        // ================= Phase C: logits tile (it, vt=jt) =================
        if (tid < 32) {
            while (flag_ld(&gates_slot[it * 32 + tid]) < (unsigned)(ty + 1)) {}
        }

        f32x4 lacc = {0.f,0.f,0.f,0.f};
        {
            const int rW = tid >> 3;          // 0..31
            const int qW = (tid & 7) * 32;
            for (int ch = 0; ch < 2; ++ch) {
                const int kc0 = ch * 256;
                __syncthreads();
                #pragma unroll 8
                for (int r = 0; r < 32; ++r) {
                    float v = agent_ld(&sn[(size_t)(i0 + r) * 512 + kc0 + tid]);
                    unsigned short hi, lo;
                    split_bf16(v, hi, lo);
                    Ah[r * D_STR + tid] = hi;
                    Al[r * D_STR + tid] = lo;
                }
                {
                    const size_t base = (size_t)(v0 + rW) * 512 + kc0 + qW;
                    #pragma unroll
                    for (int i = 0; i < 4; ++i) {
                        *(bf16x8*)&Wh[rW * D_STR + qW + i * 8] = *(const bf16x8*)&Wfh[base + i * 8];
                        *(bf16x8*)&Wl[rW * D_STR + qW + i * 8] = *(const bf16x8*)&Wfl[base + i * 8];
                    }
                }
                __syncthreads();
                #pragma unroll
                for (int kc = 0; kc < 8; ++kc) {
                    bf16x8 fah = *(const bf16x8*)(pAh + kc * 32);
                    bf16x8 fal = *(const bf16x8*)(pAl + kc * 32);
                    bf16x8 wh  = *(const bf16x8*)(pLWh + kc * 32);
                    bf16x8 wl  = *(const bf16x8*)(pLWl + kc * 32);
                    lacc = __builtin_amdgcn_mfma_f32_16x16x32_bf16(fal, wh, lacc, 0, 0, 0);
                    lacc = __builtin_amdgcn_mfma_f32_16x16x32_bf16(fah, wl, lacc, 0, 0, 0);
                    lacc = __builtin_amdgcn_mfma_f32_16x16x32_bf16(fah, wh, lacc, 0, 0, 0);
                }
            }
        }
        #pragma unroll
        for (int reg = 0; reg < 4; ++reg) {
            int row = i0 + rt * 16 + quad * 4 + reg;
            int col = v0 + ct * 16 + ln;
            out[(size_t)row * (TYN * VOCAB) + ty * VOCAB + col] = lacc[reg] + bfc[col];
        }
        __syncthreads();   // all s reads + LDS use complete before flag
        if (tid == 0) flag_st(&log_slot[it * 32 + jt], (unsigned)(ty + 1));
    }
}

extern "C" void kernel_launch(void* const* d_in, const int* in_sizes, int n_in,
                              void* d_out, int out_size, void* d_ws, size_t ws_size,
                              hipStream_t stream)
{
    const float* X     = (const float*)d_in[0];
    const float* Wih_f = (const float*)d_in[1];
    const float* Whh_f = (const float*)d_in[2];
    const float* b_f   = (const float*)d_in[3];
    const float* Wih_b = (const float*)d_in[4];
    const float* Whh_b = (const float*)d_in[5];
    const float* b_b   = (const float*)d_in[6];
    const float* W1    = (const float*)d_in[7];
    const float* b1    = (const float*)d_in[8];
    const float* W2    = (const float*)d_in[9];
    const float* b2    = (const float*)d_in[10];
    const float* Wc_ih = (const float*)d_in[11];
    const float* Wc_hh = (const float*)d_in[12];
    const float* bc    = (const float*)d_in[13];
    const float* Wfc   = (const float*)d_in[14];
    const float* bfc   = (const float*)d_in[15];
    float* out = (float*)d_out;
    float* ws  = (float*)d_ws;

    // workspace layout (float offsets) — NO overlaps:
    float* sbufA = ws;                    // 256*512          [0 .. 131072)
    float* sbufB = ws + 131072;           // 256*512          [131072 .. 262144)
    float* xcat  = ws + 262144;           // 256*512 ctx      [262144 .. 393216)
    float* a     = ws + 524288;           // 256*256*512      [524288 .. 34078720)
    float* aW1   = ws + 34078720;         // 65536*10         [.. 34734080)
    unsigned short* Wch = (unsigned short*)(ws + 34734080);   // [.. 35782656)
    unsigned short* Wcl = (unsigned short*)(ws + 35782656);   // [.. 36831232)
    unsigned short* Wfh = (unsigned short*)(ws + 36831232);   // [.. 37093376)
    unsigned short* Wfl = (unsigned short*)(ws + 37093376);   // [.. 37355520)
    unsigned int* dslots = (unsigned int*)(ws + 37355520);    // 768 uints [.. 37356288)
    unsigned int* bar    = (unsigned int*)(ws + 37356288);    // 256 uints [.. 37356544)

    static int attrs_set = 0;
    if (!attrs_set) {
        hipFuncSetAttribute(reinterpret_cast<const void*>(encoder_kernel),
                            hipFuncAttributeMaxDynamicSharedMemorySize, ENC_LDS_BYTES);
        hipFuncSetAttribute(reinterpret_cast<const void*>(decoder_kernel),
                            hipFuncAttributeMaxDynamicSharedMemorySize, DEC_LDS_BYTES);
        attrs_set = 1;
    }

    // zero s(0) parity buffer, decoder flag slots, encoder flags
    hipMemsetAsync(sbufA, 0, (size_t)131072 * sizeof(float), stream);
    hipMemsetAsync(dslots, 0, (768 + 256) * sizeof(unsigned int), stream);

    wsplit_cat<<<8192, 256, 0, stream>>>(Wc_ih, Wc_hh, Wch, Wcl);
    wsplit_fc<<<2048, 256, 0, stream>>>(Wfc, Wfh, Wfl);

    {
        void* args[] = { (void*)&X, (void*)&Wih_f, (void*)&Whh_f, (void*)&b_f,
                         (void*)&Wih_b, (void*)&Whh_b, (void*)&b_b, (void*)&a, (void*)&bar };
        hipLaunchCooperativeKernel(reinterpret_cast<void*>(encoder_kernel),
                                   dim3(256), dim3(256), args, ENC_LDS_BYTES, stream);
    }

    attn_prep<<<1024, 256, 0, stream>>>(a, W1, b1, aW1);

    {
        void* args[] = { (void*)&aW1, (void*)&a, (void*)&W1, (void*)&W2, (void*)&b2,
                         (void*)&Wch, (void*)&Wcl, (void*)&bc,
                         (void*)&Wfh, (void*)&Wfl, (void*)&bfc,
                         (void*)&sbufA, (void*)&sbufB, (void*)&xcat,
                         (void*)&out, (void*)&dslots };
        hipLaunchCooperativeKernel(reinterpret_cast<void*>(decoder_kernel),
                                   dim3(256), dim3(256), args, DEC_LDS_BYTES, stream);
    }
}

// Round 11
// 2139.894 us; speedup vs baseline: 1.1333x; 1.1333x over previous
//
#include <hip/hip_runtime.h>
#include <hip/hip_bf16.h>
#include <hip/hip_cooperative_groups.h>

namespace cg = cooperative_groups;

#define TXN 256   // Tx
#define NA 256    // n_a
#define NF 128    // features
#define NS 512    // n_s
#define TYN 10
#define VOCAB 1024

// ---- encoder LDS layout (split-bf16 planes) ----
#define A_STR 392
#define W_STR 392
#define WL_OFF (64 * W_STR)
#define AH_OFF (2 * 64 * W_STR)
#define AL_OFF (AH_OFF + 32 * A_STR)
#define PRE_OFF_US (AL_OFF + 32 * A_STR)
#define ENC_LDS_BYTES (150528 + 32 * 68 * 4 + 64 * 4)   // 159,488 B

// ---- decoder MFMA-GEMM LDS layout (ushort indices), K-chunk = 256 ----
#define D_STR 264                        // 256 + 8 pad
#define D_WH 0
#define D_WL (64 * D_STR)                // 16896
#define D_AH (2 * 64 * D_STR)            // 33792
#define D_AL (D_AH + 32 * D_STR)         // 42240
#define D_PRE_US (D_AL + 32 * D_STR)     // 50688 -> byte 101376
#define DEC_LDS_BYTES (101376 + 32 * 68 * 4 + 64 * 4)   // 110,336 B

typedef __attribute__((ext_vector_type(8))) short bf16x8;
typedef __attribute__((ext_vector_type(4))) float f32x4;

__device__ __forceinline__ float fsigmoid(float x) { return 1.f / (1.f + __expf(-x)); }
__device__ __forceinline__ float ftanh(float x)    { return 1.f - 2.f / (1.f + __expf(2.f * x)); }

__device__ __forceinline__ void split_bf16(float v, unsigned short& hi, unsigned short& lo) {
    __hip_bfloat16 h = __float2bfloat16(v);
    float rem = v - __bfloat162float(h);
    __hip_bfloat16 l = __float2bfloat16(rem);
    hi = *reinterpret_cast<unsigned short*>(&h);
    lo = *reinterpret_cast<unsigned short*>(&l);
}

__device__ __forceinline__ float agent_ld(const float* p) {
    return __hip_atomic_load(p, __ATOMIC_RELAXED, __HIP_MEMORY_SCOPE_AGENT);
}
__device__ __forceinline__ void agent_st(float* p, float v) {
    __hip_atomic_store(p, v, __ATOMIC_RELAXED, __HIP_MEMORY_SCOPE_AGENT);
}
__device__ __forceinline__ unsigned flag_ld(const unsigned* p) {
    return __hip_atomic_load(p, __ATOMIC_RELAXED, __HIP_MEMORY_SCOPE_AGENT);
}
__device__ __forceinline__ void flag_st(unsigned* p, unsigned v) {
    __hip_atomic_store(p, v, __ATOMIC_RELAXED, __HIP_MEMORY_SCOPE_AGENT);
}

// ---------------------------------------------------------------------------
// Persistent bidirectional LSTM encoder — MFMA split-bf16, per-producer flags.
// (unchanged from R7, verified passing)
// ---------------------------------------------------------------------------
__global__ __launch_bounds__(256, 1) void encoder_kernel(
    const float* __restrict__ X,
    const float* __restrict__ Wih_f, const float* __restrict__ Whh_f, const float* __restrict__ b_f,
    const float* __restrict__ Wih_b, const float* __restrict__ Whh_b, const float* __restrict__ b_b,
    float* __restrict__ a, unsigned int* __restrict__ bar)
{
    extern __shared__ unsigned char smem_raw[];
    unsigned short* Wh  = (unsigned short*)smem_raw;
    unsigned short* Wl  = (unsigned short*)smem_raw + WL_OFF;
    unsigned short* Ahh = (unsigned short*)smem_raw + AH_OFF;
    unsigned short* All = (unsigned short*)smem_raw + AL_OFF;
    float* Pre = (float*)(smem_raw + (size_t)PRE_OFF_US * 2);   // [32][68]
    float* bsh = Pre + 32 * 68;                                  // [64]

    const int tid = threadIdx.x;
    const int dir = blockIdx.x & 1;
    const int bid = blockIdx.x >> 1;
    const int i0 = (bid >> 4) * 32;
    const int j0 = (bid & 15) * 16;
    const int grp = dir * 8 + (bid >> 4);
    const int myjb = bid & 15;
    unsigned int* slots = bar + grp * 16;

    const float* __restrict__ Wih = dir ? Wih_b : Wih_f;
    const float* __restrict__ Whh = dir ? Whh_b : Whh_f;
    const float* __restrict__ bv  = dir ? b_b  : b_f;

    const int jl = tid & 15;
    const int ip = tid >> 4;
    const int iA = ip * 2;

    if (tid < 64) bsh[tid] = bv[(tid >> 4) * NA + j0 + (tid & 15)];
    for (int r = 0; r < 64; ++r) {
        int row = (r >> 4) * NA + j0 + (r & 15);
        unsigned short hi, lo;
        split_bf16(Whh[(size_t)row * NA + tid], hi, lo);
        Wh[r * W_STR + tid] = hi;
        Wl[r * W_STR + tid] = lo;
        if (tid < NF) {
            split_bf16(Wih[(size_t)row * NF + tid], hi, lo);
            Wh[r * W_STR + 256 + tid] = hi;
            Wl[r * W_STR + 256 + tid] = lo;
        }
    }

    #pragma unroll 4
    for (int r = 0; r < 32; ++r) {
        Ahh[r * A_STR + tid] = 0;
        All[r * A_STR + tid] = 0;
    }
    {
        const int t0 = dir ? (TXN - 1) : 0;
        const int kx = tid & 127;
        const int rbase = tid >> 7;
        #pragma unroll 4
        for (int rr = 0; rr < 16; ++rr) {
            int r = rr * 2 + rbase;
            float v = X[((size_t)(i0 + r) * TXN + t0) * NF + kx];
            unsigned short hi, lo;
            split_bf16(v, hi, lo);
            Ahh[r * A_STR + 256 + kx] = hi;
            All[r * A_STR + 256 + kx] = lo;
        }
    }

    float c0 = 0.f, c1 = 0.f;

    const int lane = tid & 63;
    const int wv   = tid >> 6;
    const int rt   = wv >> 1;
    const int g0   = (wv & 1) * 2;
    const int ln   = lane & 15;
    const int quad = lane >> 4;
    const unsigned short* pAh = Ahh + (rt * 16 + ln) * A_STR + quad * 8;
    const unsigned short* pAl = All + (rt * 16 + ln) * A_STR + quad * 8;
    const unsigned short* pW0h = Wh + (g0 * 16 + ln) * W_STR + quad * 8;
    const unsigned short* pW0l = Wl + (g0 * 16 + ln) * W_STR + quad * 8;
    const unsigned short* pW1h = pW0h + 16 * W_STR;
    const unsigned short* pW1l = pW0l + 16 * W_STR;

    for (int step = 0; step < TXN; ++step) {
        const int t = dir ? (TXN - 1 - step) : step;

        if (step != 0) {
            const int tprev = dir ? (t + 1) : (t - 1);
            const int jb = tid >> 4;
            while (flag_ld(&slots[jb]) < (unsigned)step) {}
            float hv[32];
            #pragma unroll
            for (int r = 0; r < 32; ++r) {
                hv[r] = agent_ld(&a[(((size_t)(i0 + r) * TXN + tprev) << 9) + dir * NA + tid]);
            }
            #pragma unroll
            for (int r = 0; r < 32; ++r) {
                unsigned short hi, lo;
                split_bf16(hv[r], hi, lo);
                Ahh[r * A_STR + tid] = hi;
                All[r * A_STR + tid] = lo;
            }
        }
        __syncthreads();

        f32x4 a0e = {0.f,0.f,0.f,0.f}, a0o = {0.f,0.f,0.f,0.f};
        f32x4 a1e = {0.f,0.f,0.f,0.f}, a1o = {0.f,0.f,0.f,0.f};
        #pragma unroll
        for (int kp = 0; kp < 6; ++kp) {
            {
                const int kc = kp * 2;
                bf16x8 fah = *(const bf16x8*)(pAh + kc * 32);
                bf16x8 fal = *(const bf16x8*)(pAl + kc * 32);
                bf16x8 w0h = *(const bf16x8*)(pW0h + kc * 32);
                bf16x8 w0l = *(const bf16x8*)(pW0l + kc * 32);
                bf16x8 w1h = *(const bf16x8*)(pW1h + kc * 32);
                bf16x8 w1l = *(const bf16x8*)(pW1l + kc * 32);
                a0e = __builtin_amdgcn_mfma_f32_16x16x32_bf16(fal, w0h, a0e, 0, 0, 0);
                a0e = __builtin_amdgcn_mfma_f32_16x16x32_bf16(fah, w0l, a0e, 0, 0, 0);
                a0e = __builtin_amdgcn_mfma_f32_16x16x32_bf16(fah, w0h, a0e, 0, 0, 0);
                a1e = __builtin_amdgcn_mfma_f32_16x16x32_bf16(fal, w1h, a1e, 0, 0, 0);
                a1e = __builtin_amdgcn_mfma_f32_16x16x32_bf16(fah, w1l, a1e, 0, 0, 0);
                a1e = __builtin_amdgcn_mfma_f32_16x16x32_bf16(fah, w1h, a1e, 0, 0, 0);
            }
            {
                const int kc = kp * 2 + 1;
                bf16x8 fah = *(const bf16x8*)(pAh + kc * 32);
                bf16x8 fal = *(const bf16x8*)(pAl + kc * 32);
                bf16x8 w0h = *(const bf16x8*)(pW0h + kc * 32);
                bf16x8 w0l = *(const bf16x8*)(pW0l + kc * 32);
                bf16x8 w1h = *(const bf16x8*)(pW1h + kc * 32);
                bf16x8 w1l = *(const bf16x8*)(pW1l + kc * 32);
                a0o = __builtin_amdgcn_mfma_f32_16x16x32_bf16(fal, w0h, a0o, 0, 0, 0);
                a0o = __builtin_amdgcn_mfma_f32_16x16x32_bf16(fah, w0l, a0o, 0, 0, 0);
                a0o = __builtin_amdgcn_mfma_f32_16x16x32_bf16(fah, w0h, a0o, 0, 0, 0);
                a1o = __builtin_amdgcn_mfma_f32_16x16x32_bf16(fal, w1h, a1o, 0, 0, 0);
                a1o = __builtin_amdgcn_mfma_f32_16x16x32_bf16(fah, w1l, a1o, 0, 0, 0);
                a1o = __builtin_amdgcn_mfma_f32_16x16x32_bf16(fah, w1h, a1o, 0, 0, 0);
            }
        }
        #pragma unroll
        for (int reg = 0; reg < 4; ++reg) {
            int prow = rt * 16 + quad * 4 + reg;
            Pre[prow * 68 + g0 * 16 + ln]       = a0e[reg] + a0o[reg];
            Pre[prow * 68 + (g0 + 1) * 16 + ln] = a1e[reg] + a1o[reg];
        }
        __syncthreads();

        float h0, h1;
        {
            float gi = fsigmoid(Pre[iA * 68 +      jl] + bsh[jl]);
            float gf = fsigmoid(Pre[iA * 68 + 16 + jl] + bsh[16 + jl]);
            float gg = ftanh  (Pre[iA * 68 + 32 + jl] + bsh[32 + jl]);
            float go = fsigmoid(Pre[iA * 68 + 48 + jl] + bsh[48 + jl]);
            c0 = gf * c0 + gi * gg;
            h0 = go * ftanh(c0);
        }
        {
            float gi = fsigmoid(Pre[(iA + 1) * 68 +      jl] + bsh[jl]);
            float gf = fsigmoid(Pre[(iA + 1) * 68 + 16 + jl] + bsh[16 + jl]);
            float gg = ftanh  (Pre[(iA + 1) * 68 + 32 + jl] + bsh[32 + jl]);
            float go = fsigmoid(Pre[(iA + 1) * 68 + 48 + jl] + bsh[48 + jl]);
            c1 = gf * c1 + gi * gg;
            h1 = go * ftanh(c1);
        }
        agent_st(&a[(((size_t)(i0 + iA)     * TXN + t) << 9) + dir * NA + j0 + jl], h0);
        agent_st(&a[(((size_t)(i0 + iA + 1) * TXN + t) << 9) + dir * NA + j0 + jl], h1);

        if (step != TXN - 1) {
            __syncthreads();
            if (tid == 0) flag_st(&slots[myjb], (unsigned)(step + 1));
            {
                const int tn = dir ? (t - 1) : (t + 1);
                const int kx = tid & 127;
                const int rbase = tid >> 7;
                #pragma unroll 4
                for (int rr = 0; rr < 16; ++rr) {
                    int r = rr * 2 + rbase;
                    float v = X[((size_t)(i0 + r) * TXN + tn) * NF + kx];
                    unsigned short hi, lo;
                    split_bf16(v, hi, lo);
                    Ahh[r * A_STR + 256 + kx] = hi;
                    All[r * A_STR + 256 + kx] = lo;
                }
            }
        }
    }
}

// ---------------------------------------------------------------------------
// Weight split kernels: fp32 -> bf16 hi/lo planes.
// ---------------------------------------------------------------------------
__global__ __launch_bounds__(256) void wsplit_cat(
    const float* __restrict__ Wc_ih, const float* __restrict__ Wc_hh,
    unsigned short* __restrict__ Wh, unsigned short* __restrict__ Wl)
{
    int idx = blockIdx.x * 256 + threadIdx.x;   // 2048*1024
    int r = idx >> 10, k = idx & 1023;
    float v = (k < 512) ? Wc_ih[(size_t)r * 512 + k] : Wc_hh[(size_t)r * 512 + (k - 512)];
    unsigned short hi, lo;
    split_bf16(v, hi, lo);
    Wh[idx] = hi; Wl[idx] = lo;
}

__global__ __launch_bounds__(256) void wsplit_fc(
    const float* __restrict__ Wfc,
    unsigned short* __restrict__ Wh, unsigned short* __restrict__ Wl)
{
    int idx = blockIdx.x * 256 + threadIdx.x;   // 1024*512
    unsigned short hi, lo;
    split_bf16(Wfc[idx], hi, lo);
    Wh[idx] = hi; Wl[idx] = lo;
}

// ---------------------------------------------------------------------------
// Tall-skinny: aW1[m*Tx][10] = a[m*Tx][512] @ W1[:, :512]^T + b1
// ---------------------------------------------------------------------------
__global__ __launch_bounds__(256) void attn_prep(
    const float* __restrict__ a, const float* __restrict__ W1,
    const float* __restrict__ b1, float* __restrict__ aW1)
{
    __shared__ float Wsh[10][516];
    __shared__ float red[64][10][4];
    const int tid = threadIdx.x;
    for (int idx = tid; idx < 10 * 512; idx += 256) {
        int o = idx >> 9, k = idx & 511;
        Wsh[o][k] = W1[o * 1024 + k];
    }
    __syncthreads();
    const int r = tid >> 2, kq = tid & 3;
    const float* ar = a + ((size_t)blockIdx.x * 64 + r) * 512 + kq * 128;
    float acc[10] = {};
    for (int k = 0; k < 128; k += 4) {
        float4 v = *(const float4*)&ar[k];
        #pragma unroll
        for (int o = 0; o < 10; ++o) {
            float4 w = *(const float4*)&Wsh[o][kq * 128 + k];
            acc[o] += v.x * w.x + v.y * w.y + v.z * w.z + v.w * w.w;
        }
    }
    #pragma unroll
    for (int o = 0; o < 10; ++o) red[r][o][kq] = acc[o];
    __syncthreads();
    for (int idx = tid; idx < 640; idx += 256) {
        int rr = idx / 10, o = idx % 10;
        float s = red[rr][o][0] + red[rr][o][1] + red[rr][o][2] + red[rr][o][3] + b1[o];
        aW1[((size_t)blockIdx.x * 64 + rr) * 10 + o] = s;
    }
}

// ---------------------------------------------------------------------------
// Fused attention: block per batch row i (incl. in-block sW1).
// s(ty) read from s_prev with row stride sp_stride (ping-pong / S_all slot).
// ---------------------------------------------------------------------------
__global__ __launch_bounds__(256) void attn_kernel(
    const float* __restrict__ aW1,
    const float* __restrict__ s_prev, int sp_stride,
    const float* __restrict__ W1,
    const float* __restrict__ W2,
    const float* __restrict__ b2,
    const float* __restrict__ a,
    float* __restrict__ xcat)        // (m, 512) ctx only
{
    __shared__ float sh_s[10];
    __shared__ float sh_w2[10];
    __shared__ float sred[160];
    __shared__ float red[256];
    __shared__ float al[256];
    __shared__ float4 ctxred[256];
    const int i = blockIdx.x;
    const int tid = threadIdx.x;

    if (tid < 160) {
        int o = tid >> 4, part = tid & 15;
        const float* srow = s_prev + (size_t)i * sp_stride;
        const float* wrow = W1 + o * 1024 + 512;
        float p = 0.f;
        for (int k = part; k < 512; k += 16) p += srow[k] * wrow[k];
        sred[tid] = p;
    }
    __syncthreads();
    if (tid < 10) {
        float v = 0.f;
        #pragma unroll
        for (int p = 0; p < 16; ++p) v += sred[tid * 16 + p];
        sh_s[tid] = v;
        sh_w2[tid] = W2[tid];
    }
    __syncthreads();

    float sum = b2[0];
    const float* ar = aW1 + ((size_t)i * TXN + tid) * 10;
    #pragma unroll
    for (int h = 0; h < 10; ++h) {
        float e = ftanh(ar[h] + sh_s[h]);
        sum += e * sh_w2[h];
    }
    float sc = fmaxf(sum, 0.f);

    red[tid] = sc;
    __syncthreads();
    for (int s = 128; s > 0; s >>= 1) {
        if (tid < s) red[tid] = fmaxf(red[tid], red[tid + s]);
        __syncthreads();
    }
    float mx = red[0];
    __syncthreads();
    float p = __expf(sc - mx);
    red[tid] = p;
    __syncthreads();
    for (int s = 128; s > 0; s >>= 1) {
        if (tid < s) red[tid] += red[tid + s];
        __syncthreads();
    }
    float inv = 1.f / red[0];
    al[tid] = p * inv;
    __syncthreads();

    const int half = tid >> 7;
    const int q    = tid & 127;
    const float* abase = a + (size_t)i * TXN * NS + q * 4;
    float4 acc = make_float4(0.f, 0.f, 0.f, 0.f);
    #pragma unroll 8
    for (int t = half; t < TXN; t += 2) {
        float w = al[t];
        float4 v = *(const float4*)&abase[(size_t)t * NS];
        acc.x += w * v.x; acc.y += w * v.y; acc.z += w * v.z; acc.w += w * v.w;
    }
    ctxred[tid] = acc;
    __syncthreads();
    if (tid < 128) {
        float4 e = ctxred[tid];
        float4 o = ctxred[tid + 128];
        float4 r4 = make_float4(e.x + o.x, e.y + o.y, e.z + o.z, e.w + o.w);
        *(float4*)&xcat[(size_t)i * 512 + tid * 4] = r4;
    }
}

// ---------------------------------------------------------------------------
// Decoder gates GEMM (MFMA split-bf16) + fused LSTM cell epilogue.
// A-cols 0..511 = ctx (xcat), 512..1023 = s(ty) from s_prev (stride sp_stride).
// Writes s(ty+1) into s_out (stride so_stride). No WAR: s_out != s_prev.
// ---------------------------------------------------------------------------
__global__ __launch_bounds__(256, 1) void gates_kernel(
    const float* __restrict__ xcat,          // (256, 512) ctx
    const float* __restrict__ s_prev, int sp_stride,
    const unsigned short* __restrict__ Wch,
    const unsigned short* __restrict__ Wcl,
    const float* __restrict__ bc,
    float* __restrict__ c_buf,               // (256, 512)
    float* __restrict__ s_out, int so_stride)
{
    extern __shared__ unsigned char smem_raw[];
    unsigned short* Wh = (unsigned short*)smem_raw + D_WH;
    unsigned short* Wl = (unsigned short*)smem_raw + D_WL;
    unsigned short* Ah = (unsigned short*)smem_raw + D_AH;
    unsigned short* Al = (unsigned short*)smem_raw + D_AL;
    float* Pre = (float*)(smem_raw + (size_t)D_PRE_US * 2);   // [32][68]
    float* bsh = Pre + 32 * 68;                                // [64]

    const int tid = threadIdx.x;
    const int i0 = blockIdx.x * 32;
    const int j0 = blockIdx.y * 16;

    if (tid < 64) bsh[tid] = bc[(tid >> 4) * 512 + j0 + (tid & 15)];

    const int lane = tid & 63;
    const int wv   = tid >> 6;
    const int rt   = wv >> 1;
    const int g0   = (wv & 1) * 2;
    const int ln   = lane & 15;
    const int quad = lane >> 4;
    const unsigned short* pAh = Ah + (rt * 16 + ln) * D_STR + quad * 8;
    const unsigned short* pAl = Al + (rt * 16 + ln) * D_STR + quad * 8;
    const unsigned short* pW0h = Wh + (g0 * 16 + ln) * D_STR + quad * 8;
    const unsigned short* pW0l = Wl + (g0 * 16 + ln) * D_STR + quad * 8;
    const unsigned short* pW1h = pW0h + 16 * D_STR;
    const unsigned short* pW1l = pW0l + 16 * D_STR;

    const int rW = tid >> 2;
    const int qW = (tid & 3) * 64;
    const int rowg = (rW >> 4) * 512 + j0 + (rW & 15);

    f32x4 a0 = {0.f,0.f,0.f,0.f}, a1 = {0.f,0.f,0.f,0.f};

    for (int ch = 0; ch < 4; ++ch) {
        const int kc0 = ch * 256;
        __syncthreads();
        #pragma unroll 8
        for (int r = 0; r < 32; ++r) {
            float v;
            if (ch < 2) v = xcat[(size_t)(i0 + r) * 512 + kc0 + tid];
            else        v = s_prev[(size_t)(i0 + r) * sp_stride + (kc0 - 512) + tid];
            unsigned short hi, lo;
            split_bf16(v, hi, lo);
            Ah[r * D_STR + tid] = hi;
            Al[r * D_STR + tid] = lo;
        }
        {
            const size_t base = (size_t)rowg * 1024 + kc0 + qW;
            #pragma unroll
            for (int i = 0; i < 8; ++i) {
                *(bf16x8*)&Wh[rW * D_STR + qW + i * 8] = *(const bf16x8*)&Wch[base + i * 8];
                *(bf16x8*)&Wl[rW * D_STR + qW + i * 8] = *(const bf16x8*)&Wcl[base + i * 8];
            }
        }
        __syncthreads();
        #pragma unroll
        for (int kc = 0; kc < 8; ++kc) {
            bf16x8 fah = *(const bf16x8*)(pAh + kc * 32);
            bf16x8 fal = *(const bf16x8*)(pAl + kc * 32);
            bf16x8 w0h = *(const bf16x8*)(pW0h + kc * 32);
            bf16x8 w0l = *(const bf16x8*)(pW0l + kc * 32);
            bf16x8 w1h = *(const bf16x8*)(pW1h + kc * 32);
            bf16x8 w1l = *(const bf16x8*)(pW1l + kc * 32);
            a0 = __builtin_amdgcn_mfma_f32_16x16x32_bf16(fal, w0h, a0, 0, 0, 0);
            a0 = __builtin_amdgcn_mfma_f32_16x16x32_bf16(fah, w0l, a0, 0, 0, 0);
            a0 = __builtin_amdgcn_mfma_f32_16x16x32_bf16(fah, w0h, a0, 0, 0, 0);
            a1 = __builtin_amdgcn_mfma_f32_16x16x32_bf16(fal, w1h, a1, 0, 0, 0);
            a1 = __builtin_amdgcn_mfma_f32_16x16x32_bf16(fah, w1l, a1, 0, 0, 0);
            a1 = __builtin_amdgcn_mfma_f32_16x16x32_bf16(fah, w1h, a1, 0, 0, 0);
        }
    }
    __syncthreads();
    #pragma unroll
    for (int reg = 0; reg < 4; ++reg) {
        int prow = rt * 16 + quad * 4 + reg;
        Pre[prow * 68 + g0 * 16 + ln]       = a0[reg];
        Pre[prow * 68 + (g0 + 1) * 16 + ln] = a1[reg];
    }
    __syncthreads();

    const int jl = tid & 15;
    const int iA = (tid >> 4) * 2;
    #pragma unroll
    for (int rr = 0; rr < 2; ++rr) {
        int r = iA + rr;
        float gi = fsigmoid(Pre[r * 68 +      jl] + bsh[jl]);
        float gf = fsigmoid(Pre[r * 68 + 16 + jl] + bsh[16 + jl]);
        float gg = ftanh  (Pre[r * 68 + 32 + jl] + bsh[32 + jl]);
        float go = fsigmoid(Pre[r * 68 + 48 + jl] + bsh[48 + jl]);
        size_t ci = (size_t)(i0 + r) * 512 + j0 + jl;
        float cn = gf * c_buf[ci] + gi * gg;
        c_buf[ci] = cn;
        s_out[(size_t)(i0 + r) * so_stride + j0 + jl] = go * ftanh(cn);
    }
}

// ---------------------------------------------------------------------------
// Logits GEMM (MFMA split-bf16), generalized:
// C[row, ooff+col] = S[row] @ Wfc^T + bfc, rows = gridDim.x*32.
// Deferred mode: S = S_all (2560 x 512), out stride 1024, ooff 0 (one GEMM
// for all TYN iterations). Fallback: per-iteration, stride 10240, ooff ty*1024.
// ---------------------------------------------------------------------------
__global__ __launch_bounds__(256, 1) void logits_kernel(
    const float* __restrict__ S, int s_stride,
    const unsigned short* __restrict__ Wfh,
    const unsigned short* __restrict__ Wfl,
    const float* __restrict__ bfc,
    float* __restrict__ out, int o_stride, int o_off)
{
    extern __shared__ unsigned char smem_raw[];
    unsigned short* Wh = (unsigned short*)smem_raw + D_WH;
    unsigned short* Wl = (unsigned short*)smem_raw + D_WL;
    unsigned short* Ah = (unsigned short*)smem_raw + D_AH;
    unsigned short* Al = (unsigned short*)smem_raw + D_AL;

    const int tid = threadIdx.x;
    const int i0 = blockIdx.x * 32;
    const int v0 = blockIdx.y * 64;

    const int lane = tid & 63;
    const int wv   = tid >> 6;
    const int rt   = wv >> 1;
    const int ct   = wv & 1;
    const int ln   = lane & 15;
    const int quad = lane >> 4;
    const unsigned short* pAh = Ah + (rt * 16 + ln) * D_STR + quad * 8;
    const unsigned short* pAl = Al + (rt * 16 + ln) * D_STR + quad * 8;
    const unsigned short* pW0h = Wh + (ct * 32 + ln) * D_STR + quad * 8;
    const unsigned short* pW0l = Wl + (ct * 32 + ln) * D_STR + quad * 8;
    const unsigned short* pW1h = pW0h + 16 * D_STR;
    const unsigned short* pW1l = pW0l + 16 * D_STR;

    const int rW = tid >> 2;
    const int qW = (tid & 3) * 64;

    f32x4 a0 = {0.f,0.f,0.f,0.f}, a1 = {0.f,0.f,0.f,0.f};

    for (int ch = 0; ch < 2; ++ch) {
        const int kc0 = ch * 256;
        __syncthreads();
        #pragma unroll 8
        for (int r = 0; r < 32; ++r) {
            float v = S[(size_t)(i0 + r) * s_stride + kc0 + tid];
            unsigned short hi, lo;
            split_bf16(v, hi, lo);
            Ah[r * D_STR + tid] = hi;
            Al[r * D_STR + tid] = lo;
        }
        {
            const size_t base = (size_t)(v0 + rW) * 512 + kc0 + qW;
            #pragma unroll
            for (int i = 0; i < 8; ++i) {
                *(bf16x8*)&Wh[rW * D_STR + qW + i * 8] = *(const bf16x8*)&Wfh[base + i * 8];
                *(bf16x8*)&Wl[rW * D_STR + qW + i * 8] = *(const bf16x8*)&Wfl[base + i * 8];
            }
        }
        __syncthreads();
        #pragma unroll
        for (int kc = 0; kc < 8; ++kc) {
            bf16x8 fah = *(const bf16x8*)(pAh + kc * 32);
            bf16x8 fal = *(const bf16x8*)(pAl + kc * 32);
            bf16x8 w0h = *(const bf16x8*)(pW0h + kc * 32);
            bf16x8 w0l = *(const bf16x8*)(pW0l + kc * 32);
            bf16x8 w1h = *(const bf16x8*)(pW1h + kc * 32);
            bf16x8 w1l = *(const bf16x8*)(pW1l + kc * 32);
            a0 = __builtin_amdgcn_mfma_f32_16x16x32_bf16(fal, w0h, a0, 0, 0, 0);
            a0 = __builtin_amdgcn_mfma_f32_16x16x32_bf16(fah, w0l, a0, 0, 0, 0);
            a0 = __builtin_amdgcn_mfma_f32_16x16x32_bf16(fah, w0h, a0, 0, 0, 0);
            a1 = __builtin_amdgcn_mfma_f32_16x16x32_bf16(fal, w1h, a1, 0, 0, 0);
            a1 = __builtin_amdgcn_mfma_f32_16x16x32_bf16(fah, w1l, a1, 0, 0, 0);
            a1 = __builtin_amdgcn_mfma_f32_16x16x32_bf16(fah, w1h, a1, 0, 0, 0);
        }
    }
    #pragma unroll
    for (int reg = 0; reg < 4; ++reg) {
        int row = i0 + rt * 16 + quad * 4 + reg;
        int col0 = v0 + ct * 32 + ln;
        out[(size_t)row * o_stride + o_off + col0]      = a0[reg] + bfc[col0];
        out[(size_t)row * o_stride + o_off + col0 + 16] = a1[reg] + bfc[col0 + 16];
    }
}

extern "C" void kernel_launch(void* const* d_in, const int* in_sizes, int n_in,
                              void* d_out, int out_size, void* d_ws, size_t ws_size,
                              hipStream_t stream)
{
    const float* X     = (const float*)d_in[0];
    const float* Wih_f = (const float*)d_in[1];
    const float* Whh_f = (const float*)d_in[2];
    const float* b_f   = (const float*)d_in[3];
    const float* Wih_b = (const float*)d_in[4];
    const float* Whh_b = (const float*)d_in[5];
    const float* b_b   = (const float*)d_in[6];
    const float* W1    = (const float*)d_in[7];
    const float* b1    = (const float*)d_in[8];
    const float* W2    = (const float*)d_in[9];
    const float* b2    = (const float*)d_in[10];
    const float* Wc_ih = (const float*)d_in[11];
    const float* Wc_hh = (const float*)d_in[12];
    const float* bc    = (const float*)d_in[13];
    const float* Wfc   = (const float*)d_in[14];
    const float* bfc   = (const float*)d_in[15];
    float* out = (float*)d_out;
    float* ws  = (float*)d_ws;

    // workspace layout (float offsets) — no overlaps:
    float* c_buf = ws;                    // [0 .. 131072)       memset 0
    float* zbuf  = ws + 131072;           // [131072 .. 262144)  memset 0 (s(0); reused as sbufA after ty=0)
    float* sbufB = ws + 262144;           // [262144 .. 393216)  fallback ping-pong
    float* xcat  = ws + 393216;           // [393216 .. 524288)  ctx (256x512)
    float* a     = ws + 524288;           // [524288 .. 34078720)
    float* aW1   = ws + 34078720;         // [.. 34734080)
    unsigned short* Wch = (unsigned short*)(ws + 34734080);   // [.. 35782656)
    unsigned short* Wcl = (unsigned short*)(ws + 35782656);   // [.. 36831232)
    unsigned short* Wfh = (unsigned short*)(ws + 36831232);   // [.. 37093376)
    unsigned short* Wfl = (unsigned short*)(ws + 37093376);   // [.. 37355520)
    unsigned int* bar   = (unsigned int*)(ws + 37355520);     // 256 uints [.. 37355776)
    float* S_all = ws + 37355776;         // 2560*512 [.. 38666496) — deferred only
    const int deferred = (ws_size >= (size_t)38666496 * sizeof(float)) ? 1 : 0;

    static int attrs_set = 0;
    if (!attrs_set) {
        hipFuncSetAttribute(reinterpret_cast<const void*>(encoder_kernel),
                            hipFuncAttributeMaxDynamicSharedMemorySize, ENC_LDS_BYTES);
        hipFuncSetAttribute(reinterpret_cast<const void*>(gates_kernel),
                            hipFuncAttributeMaxDynamicSharedMemorySize, DEC_LDS_BYTES);
        hipFuncSetAttribute(reinterpret_cast<const void*>(logits_kernel),
                            hipFuncAttributeMaxDynamicSharedMemorySize, DEC_LDS_BYTES);
        attrs_set = 1;
    }

    // zero c_buf + zbuf (contiguous) and encoder flags
    hipMemsetAsync(c_buf, 0, (size_t)262144 * sizeof(float), stream);
    hipMemsetAsync(bar, 0, 256 * sizeof(unsigned int), stream);

    wsplit_cat<<<8192, 256, 0, stream>>>(Wc_ih, Wc_hh, Wch, Wcl);
    wsplit_fc<<<2048, 256, 0, stream>>>(Wfc, Wfh, Wfl);

    {
        void* args[] = { (void*)&X, (void*)&Wih_f, (void*)&Whh_f, (void*)&b_f,
                         (void*)&Wih_b, (void*)&Whh_b, (void*)&b_b, (void*)&a, (void*)&bar };
        hipLaunchCooperativeKernel(reinterpret_cast<void*>(encoder_kernel),
                                   dim3(256), dim3(256), args, ENC_LDS_BYTES, stream);
    }

    attn_prep<<<1024, 256, 0, stream>>>(a, W1, b1, aW1);

    for (int ty = 0; ty < TYN; ++ty) {
        const float* sprev; int spstr;
        float* sout; int sostr;
        if (ty == 0) { sprev = zbuf; spstr = 512; }
        else if (deferred) { sprev = S_all + (size_t)(ty - 1) * 512; spstr = TYN * 512; }
        else { sprev = (ty & 1) ? sbufB : zbuf; spstr = 512; }
        if (deferred) { sout = S_all + (size_t)ty * 512; sostr = TYN * 512; }
        else { sout = (ty & 1) ? zbuf : sbufB; sostr = 512; }

        attn_kernel<<<256, 256, 0, stream>>>(aW1, sprev, spstr, W1, W2, b2, a, xcat);
        gates_kernel<<<dim3(8, 32), 256, DEC_LDS_BYTES, stream>>>(
            xcat, sprev, spstr, Wch, Wcl, bc, c_buf, sout, sostr);
        if (!deferred) {
            logits_kernel<<<dim3(8, 16), 256, DEC_LDS_BYTES, stream>>>(
                sout, 512, Wfh, Wfl, bfc, out, TYN * VOCAB, ty * VOCAB);
        }
    }
    if (deferred) {
        // one batched GEMM: out(2560,1024) = S_all(2560,512) @ Wfc^T + bfc
        logits_kernel<<<dim3(80, 16), 256, DEC_LDS_BYTES, stream>>>(
            S_all, 512, Wfh, Wfl, bfc, out, VOCAB, 0);
    }
}